// Round 1
// baseline (623.943 us; speedup 1.0000x reference)
//
#include <hip/hip_runtime.h>
#include <math.h>

// Problem constants: inputs (32,64,64,64) BCHW fp32, codebook (1024,64) fp32
#define TB       256
#define NBLK     512            // 131072 points / 256
#define KCB      1024
#define CHUNK    128
#define NPTS     131072
#define Q_OFF    1
#define PERP_OFF 8388609
#define OH_OFF   8388610        // byte offset % 16 == 8 -> float2 only
#define LOSS_N   8388608.0f

// ws layout (4-byte units):
// [0,1024)            cnorm  (float)
// [1024,2048)         hist   (int)
// [2048,2560)         block loss partials (float)
// [2560,2560+131072)  idx    (int)

__global__ __launch_bounds__(256) void k0_prep(const float* __restrict__ cb,
                                               float* __restrict__ cnorm,
                                               int* __restrict__ hist) {
  int k = blockIdx.x * 256 + threadIdx.x;   // grid = 4 blocks -> k in [0,1024)
  hist[k] = 0;
  const float4* row = (const float4*)(cb + (size_t)k * 64);
  float s = 0.f;
#pragma unroll
  for (int i = 0; i < 16; ++i) {
    float4 v = row[i];
    s += v.x * v.x + v.y * v.y + v.z * v.z + v.w * v.w;
  }
  cnorm[k] = s;
}

__global__ __launch_bounds__(256, 4) void k1_main(
    const float* __restrict__ in, const float* __restrict__ cb,
    const float* __restrict__ cnorm, int* __restrict__ hist,
    float* __restrict__ partial, int* __restrict__ idx,
    float* __restrict__ out) {
  __shared__ float lds_cb[CHUNK * 64];
  __shared__ float lds_cn[CHUNK];

  const int tid = threadIdx.x;
  const int n  = blockIdx.x * TB + tid;
  const int b  = n >> 12;          // batch
  const int hw = n & 4095;         // h*64+w

  // Load this point's 64 channels (BCHW: stride 4096 floats per channel).
  const float* xp = in + ((size_t)b << 18) + hw;
  float x[64];
#pragma unroll
  for (int c = 0; c < 64; ++c) x[c] = xp[(size_t)c << 12];

  float bestd = 3.4e38f;
  int bestk = 0;

  float2* ohz = (float2*)(out + OH_OFF);
  const size_t zbase = (size_t)blockIdx.x * 131072 + tid;

  for (int k0 = 0; k0 < KCB; k0 += CHUNK) {
    __syncthreads();
    // Stage 128 codes (32 KiB) into LDS, coalesced float4.
    const float4* src = (const float4*)(cb + (size_t)k0 * 64);
    float4* dst = (float4*)lds_cb;
#pragma unroll
    for (int i = 0; i < 8; ++i) dst[tid + 256 * i] = src[tid + 256 * i];
    if (tid < CHUNK) lds_cn[tid] = cnorm[k0 + tid];
    __syncthreads();

    // Interleave 1/8 of the 512 MiB one-hot zero-fill with this chunk's
    // compute so HBM stores overlap the VALU-bound distance loop.
    {
      size_t zb = zbase + (size_t)(k0 >> 7) * 16384;
#pragma unroll 4
      for (int i = 0; i < 64; ++i) ohz[zb + (size_t)i * 256] = make_float2(0.f, 0.f);
    }

    for (int kk = 0; kk < CHUNK; ++kk) {
      const float4* row = (const float4*)(lds_cb + kk * 64);  // broadcast reads
      float d0 = 0.f, d1 = 0.f, d2 = 0.f, d3 = 0.f;
#pragma unroll
      for (int c4 = 0; c4 < 16; ++c4) {
        float4 v = row[c4];
        d0 = fmaf(x[c4 * 4 + 0], v.x, d0);
        d1 = fmaf(x[c4 * 4 + 1], v.y, d1);
        d2 = fmaf(x[c4 * 4 + 2], v.z, d2);
        d3 = fmaf(x[c4 * 4 + 3], v.w, d3);
      }
      float dot = (d0 + d1) + (d2 + d3);
      float d = fmaf(-2.f, dot, lds_cn[kk]);   // ||c||^2 - 2 x.c
      if (d < bestd) { bestd = d; bestk = k0 + kk; }  // strict < = first-index tie-break
    }
  }

  idx[n] = bestk;
  atomicAdd(&hist[bestk], 1);   // integer atomic: deterministic

  // quantized = codebook[bestk]; straight-through out = x + (q - x); loss partial
  const float4* qrow = (const float4*)(cb + (size_t)bestk * 64);
  float* outq = out + Q_OFF + ((size_t)b << 18) + hw;
  float lsum = 0.f;
#pragma unroll
  for (int c4 = 0; c4 < 16; ++c4) {
    float4 q = qrow[c4];
    float qv[4] = {q.x, q.y, q.z, q.w};
#pragma unroll
    for (int j = 0; j < 4; ++j) {
      int c = c4 * 4 + j;
      float f = qv[j] - x[c];
      lsum += f * f;
      outq[(size_t)c << 12] = x[c] + f;   // emulate x + stopgrad(q - x)
    }
  }

  // Deterministic block tree-reduction of loss partial.
  __syncthreads();
  float* red = lds_cb;  // reuse LDS
  red[tid] = lsum;
  __syncthreads();
#pragma unroll
  for (int s = 128; s > 0; s >>= 1) {
    if (tid < s) red[tid] += red[tid + s];
    __syncthreads();
  }
  if (tid == 0) partial[blockIdx.x] = red[0];
}

__global__ __launch_bounds__(1024) void k2_finalize(const int* __restrict__ hist,
                                                    const float* __restrict__ partial,
                                                    float* __restrict__ out) {
  __shared__ float red[1024];
  int tid = threadIdx.x;

  // loss = 0.25 * mean((q-x)^2)
  red[tid] = (tid < 512) ? partial[tid] : 0.f;
  __syncthreads();
  for (int s = 512; s > 0; s >>= 1) {
    if (tid < s) red[tid] += red[tid + s];
    __syncthreads();
  }
  if (tid == 0) out[0] = 0.25f * (red[0] / LOSS_N);
  __syncthreads();

  // perplexity = exp(-sum p*log(p+1e-10)), p = count / N
  float p = (float)hist[tid] * (1.0f / 131072.0f);  // 2^-17: exact
  red[tid] = p * logf(p + 1e-10f);
  __syncthreads();
  for (int s = 512; s > 0; s >>= 1) {
    if (tid < s) red[tid] += red[tid + s];
    __syncthreads();
  }
  if (tid == 0) out[PERP_OFF] = expf(-red[0]);
}

__global__ __launch_bounds__(256) void k3_scatter(const int* __restrict__ idx,
                                                  float* __restrict__ out) {
  int n = blockIdx.x * 256 + threadIdx.x;
  int k = idx[n];
  int b = n >> 12;
  int pos = n & 4095;
  out[OH_OFF + ((((size_t)b << 10) + k) << 12) + pos] = 1.0f;
}

extern "C" void kernel_launch(void* const* d_in, const int* in_sizes, int n_in,
                              void* d_out, int out_size, void* d_ws, size_t ws_size,
                              hipStream_t stream) {
  const float* in = (const float*)d_in[0];
  const float* cb = (const float*)d_in[1];
  float* out = (float*)d_out;

  float* cnorm   = (float*)d_ws;
  int*   hist    = (int*)d_ws + 1024;
  float* partial = (float*)d_ws + 2048;
  int*   idx     = (int*)d_ws + 2560;

  k0_prep<<<4, 256, 0, stream>>>(cb, cnorm, hist);
  k1_main<<<NBLK, TB, 0, stream>>>(in, cb, cnorm, hist, partial, idx, out);
  k2_finalize<<<1, 1024, 0, stream>>>(hist, partial, out);
  k3_scatter<<<NBLK, TB, 0, stream>>>(idx, out);
}

// Round 2
// 414.794 us; speedup vs baseline: 1.5042x; 1.5042x over previous
//
#include <hip/hip_runtime.h>
#include <math.h>

// Problem constants: inputs (32,64,64,64) BCHW fp32, codebook (1024,64) fp32
#define TB       512           // 2 K-halves x 256 points
#define NBLK     512           // 131072 points / 256 points-per-block
#define KCB      1024
#define NPTS     131072
#define Q_OFF    1
#define PERP_OFF 8388609
#define OH_OFF   8388610       // byte offset % 16 == 8 -> float2 only
#define LOSS_N   8388608.0f

// ws layout (4-byte units):
// [0,1024)            cnorm  (float)
// [1024,2048)         hist   (int)
// [2048,2560)         block loss partials (float)
// [2560,2560+131072)  idx    (int)

__global__ __launch_bounds__(256) void k0_prep(const float* __restrict__ cb,
                                               float* __restrict__ cnorm,
                                               int* __restrict__ hist) {
  int k = blockIdx.x * 256 + threadIdx.x;   // grid = 4 blocks -> k in [0,1024)
  hist[k] = 0;
  const float4* row = (const float4*)(cb + (size_t)k * 64);
  float s = 0.f;
#pragma unroll
  for (int i = 0; i < 16; ++i) {
    float4 v = row[i];
    s += v.x * v.x + v.y * v.y + v.z * v.z + v.w * v.w;
  }
  cnorm[k] = s;
}

// 512 threads: thread t owns point (blk*256 + (t&255)) and scans codebook
// half (t>>8). Codebook rows are wave-uniform -> scalar (SGPR) loads; the
// vector-memory/LDS pipe stays free for the interleaved one-hot zero-fill.
__global__ __launch_bounds__(512, 4) void k1_main(
    const float* __restrict__ in, const float* __restrict__ cb,
    const float* __restrict__ cnorm, int* __restrict__ hist,
    float* __restrict__ partial, int* __restrict__ idx,
    float* __restrict__ out) {
  __shared__ float sd[TB];
  __shared__ int   sk[TB];

  const int tid  = threadIdx.x;
  const int pid  = tid & 255;
  const int half = tid >> 8;
  const int n  = blockIdx.x * 256 + pid;
  const int b  = n >> 12;          // batch
  const int hw = n & 4095;         // h*64+w

  // This point's 64 channels (BCHW: stride 4096 floats per channel).
  const float* xp = in + ((size_t)b << 18) + hw;
  float x[64];
#pragma unroll
  for (int c = 0; c < 64; ++c) x[c] = xp[(size_t)c << 12];

  float bestd = 3.4e38f;
  int bestk = 0;

  float2* ohz = (float2*)(out + OH_OFF);
  const float2 z2 = make_float2(0.f, 0.f);

  for (int chunk = 0; chunk < 4; ++chunk) {
    // Interleave 1/4 of this block's 1 MiB one-hot zero-fill slab with the
    // compute so HBM stores overlap the VALU-bound distance loop.
    {
      size_t zb = (size_t)blockIdx.x * 131072 + (size_t)chunk * 32768 + tid;
#pragma unroll 8
      for (int i = 0; i < 64; ++i) ohz[zb + (size_t)i * 512] = z2;
    }

    const int k0 = (half << 9) + (chunk << 7);
    for (int kk = 0; kk < 128; ++kk) {
      const int k = k0 + kk;
      // Force wave-uniform address -> s_load_dwordx16 codebook stream.
      const int ku = __builtin_amdgcn_readfirstlane(k);
      const float4* row = (const float4*)(cb + (size_t)ku * 64);
      const float cn = cnorm[ku];
      float d0 = 0.f, d1 = 0.f, d2 = 0.f, d3 = 0.f;
#pragma unroll
      for (int c4 = 0; c4 < 16; ++c4) {
        float4 v = row[c4];                 // SGPR operands into v_fma
        d0 = fmaf(x[c4 * 4 + 0], v.x, d0);
        d1 = fmaf(x[c4 * 4 + 1], v.y, d1);
        d2 = fmaf(x[c4 * 4 + 2], v.z, d2);
        d3 = fmaf(x[c4 * 4 + 3], v.w, d3);
      }
      float d = fmaf(-2.f, (d0 + d1) + (d2 + d3), cn);  // ||c||^2 - 2 x.c
      if (d < bestd) { bestd = d; bestk = k; }  // strict < = first-index tie-break
    }
  }

  // Combine the two K-halves per point (lower k wins ties: strict <).
  sd[tid] = bestd; sk[tid] = bestk;
  __syncthreads();

  float lsum = 0.f;
  if (tid < 256) {
    float od = sd[tid + 256]; int ok = sk[tid + 256];
    if (od < bestd) { bestd = od; bestk = ok; }
    idx[n] = bestk;
    atomicAdd(&hist[bestk], 1);   // integer atomic: deterministic

    // quantized = codebook[bestk]; straight-through out = x + (q - x)
    const float4* qrow = (const float4*)(cb + (size_t)bestk * 64);
    float* outq = out + Q_OFF + ((size_t)b << 18) + hw;
#pragma unroll
    for (int c4 = 0; c4 < 16; ++c4) {
      float4 q = qrow[c4];
      float qv[4] = {q.x, q.y, q.z, q.w};
#pragma unroll
      for (int j = 0; j < 4; ++j) {
        int c = c4 * 4 + j;
        float f = qv[j] - x[c];
        lsum += f * f;
        outq[(size_t)c << 12] = x[c] + f;
      }
    }
  }

  // Deterministic block tree-reduction of loss partial (all 512 threads).
  __syncthreads();
  sd[tid] = lsum;
  __syncthreads();
#pragma unroll
  for (int s = 256; s > 0; s >>= 1) {
    if (tid < s) sd[tid] += sd[tid + s];
    __syncthreads();
  }
  if (tid == 0) partial[blockIdx.x] = sd[0];
}

__global__ __launch_bounds__(1024) void k2_finalize(const int* __restrict__ hist,
                                                    const float* __restrict__ partial,
                                                    float* __restrict__ out) {
  __shared__ float red[1024];
  int tid = threadIdx.x;

  // loss = 0.25 * mean((q-x)^2)
  red[tid] = (tid < 512) ? partial[tid] : 0.f;
  __syncthreads();
  for (int s = 512; s > 0; s >>= 1) {
    if (tid < s) red[tid] += red[tid + s];
    __syncthreads();
  }
  if (tid == 0) out[0] = 0.25f * (red[0] / LOSS_N);
  __syncthreads();

  // perplexity = exp(-sum p*log(p+1e-10)), p = count / N
  float p = (float)hist[tid] * (1.0f / 131072.0f);  // 2^-17: exact
  red[tid] = p * logf(p + 1e-10f);
  __syncthreads();
  for (int s = 512; s > 0; s >>= 1) {
    if (tid < s) red[tid] += red[tid + s];
    __syncthreads();
  }
  if (tid == 0) out[PERP_OFF] = expf(-red[0]);
}

__global__ __launch_bounds__(256) void k3_scatter(const int* __restrict__ idx,
                                                  float* __restrict__ out) {
  int n = blockIdx.x * 256 + threadIdx.x;
  int k = idx[n];
  int b = n >> 12;
  int pos = n & 4095;
  out[OH_OFF + ((((size_t)b << 10) + k) << 12) + pos] = 1.0f;
}

extern "C" void kernel_launch(void* const* d_in, const int* in_sizes, int n_in,
                              void* d_out, int out_size, void* d_ws, size_t ws_size,
                              hipStream_t stream) {
  const float* in = (const float*)d_in[0];
  const float* cb = (const float*)d_in[1];
  float* out = (float*)d_out;

  float* cnorm   = (float*)d_ws;
  int*   hist    = (int*)d_ws + 1024;
  float* partial = (float*)d_ws + 2048;
  int*   idx     = (int*)d_ws + 2560;

  k0_prep<<<4, 256, 0, stream>>>(cb, cnorm, hist);
  k1_main<<<NBLK, TB, 0, stream>>>(in, cb, cnorm, hist, partial, idx, out);
  k2_finalize<<<1, 1024, 0, stream>>>(hist, partial, out);
  k3_scatter<<<NBLK, TB, 0, stream>>>(idx, out);
}

// Round 3
// 349.947 us; speedup vs baseline: 1.7830x; 1.1853x over previous
//
#include <hip/hip_runtime.h>
#include <math.h>

// Problem constants: inputs (32,64,64,64) BCHW fp32, codebook (1024,64) fp32
#define TB       256
#define NBLK     1024          // 131072 points / 128 points-per-block
#define KCB      1024
#define NPTS     131072
#define Q_OFF    1
#define PERP_OFF 8388609
#define OH_OFF   8388610       // byte offset % 16 == 8 -> float2 only
#define LOSS_N   8388608.0f

// ws layout (4-byte units):
// [0,1024)            cnorm  (float)
// [1024,2048)         hist   (int)
// [2048,3072)         block loss partials (float)
// [3072,3072+131072)  idx    (int)

__global__ __launch_bounds__(256) void k0_prep(const float* __restrict__ cb,
                                               float* __restrict__ cnorm,
                                               int* __restrict__ hist) {
  int k = blockIdx.x * 256 + threadIdx.x;   // grid = 4 blocks -> k in [0,1024)
  hist[k] = 0;
  const float4* row = (const float4*)(cb + (size_t)k * 64);
  float s = 0.f;
#pragma unroll
  for (int i = 0; i < 16; ++i) {
    float4 v = row[i];
    s += v.x * v.x + v.y * v.y + v.z * v.z + v.w * v.w;
  }
  cnorm[k] = s;
}

// 256 threads: thread t owns point-pair (t&63) of the block's 128 points and
// scans codebook quarter (t>>6). Each wave has uniform kg -> codebook rows are
// wave-uniform scalar (SGPR) loads; P=2 points double the FMA work per row,
// hiding scalar-load latency. x pairs are adjacent -> float2 coalesced loads.
__global__ __launch_bounds__(256, 3) void k1_main(
    const float* __restrict__ in, const float* __restrict__ cb,
    const float* __restrict__ cnorm, int* __restrict__ hist,
    float* __restrict__ partial, int* __restrict__ idx,
    float* __restrict__ out) {
  __shared__ float sd[4][128];
  __shared__ int   sk[4][128];

  const int tid  = threadIdx.x;
  const int pair = tid & 63;
  const int kg   = tid >> 6;          // wave-uniform (64-lane waves)
  const int n0 = blockIdx.x * 128 + pair * 2;   // and n0+1; same batch b
  const int b  = n0 >> 12;
  const int hw = n0 & 4095;           // even

  // Two adjacent points' 64 channels (BCHW: channel stride 4096 floats).
  const float* xp = in + ((size_t)b << 18) + hw;
  float x0[64], x1[64];
#pragma unroll
  for (int c = 0; c < 64; ++c) {
    float2 v = *(const float2*)(xp + ((size_t)c << 12));
    x0[c] = v.x; x1[c] = v.y;
  }

  float best0 = 3.4e38f, best1 = 3.4e38f;
  int bk0 = 0, bk1 = 0;

  float2* ohz = (float2*)(out + OH_OFF);
  const float2 z2 = make_float2(0.f, 0.f);

  for (int chunk = 0; chunk < 4; ++chunk) {
    // Interleave 1/4 of this block's 512 KiB one-hot zero-fill slab so the
    // HBM stores overlap the VALU-bound distance loop.
    {
      size_t zb = (size_t)blockIdx.x * 65536 + (size_t)chunk * 16384 + tid;
#pragma unroll 8
      for (int i = 0; i < 64; ++i) ohz[zb + (size_t)i * 256] = z2;
    }

    const int kbase = (kg << 8) + (chunk << 6);
    for (int kk = 0; kk < 64; ++kk) {
      const int ku = __builtin_amdgcn_readfirstlane(kbase + kk);
      const float4* row = (const float4*)(cb + (size_t)ku * 64);
      const float cn = cnorm[ku];
      float a0 = 0.f, a1 = 0.f, a2 = 0.f, a3 = 0.f;
      float b0 = 0.f, b1 = 0.f, b2 = 0.f, b3 = 0.f;
#pragma unroll
      for (int c4 = 0; c4 < 16; ++c4) {
        float4 v = row[c4];                 // SGPR operands into v_fma
        a0 = fmaf(x0[c4 * 4 + 0], v.x, a0);
        a1 = fmaf(x0[c4 * 4 + 1], v.y, a1);
        a2 = fmaf(x0[c4 * 4 + 2], v.z, a2);
        a3 = fmaf(x0[c4 * 4 + 3], v.w, a3);
        b0 = fmaf(x1[c4 * 4 + 0], v.x, b0);
        b1 = fmaf(x1[c4 * 4 + 1], v.y, b1);
        b2 = fmaf(x1[c4 * 4 + 2], v.z, b2);
        b3 = fmaf(x1[c4 * 4 + 3], v.w, b3);
      }
      float d0 = fmaf(-2.f, (a0 + a1) + (a2 + a3), cn);  // ||c||^2 - 2 x.c
      float d1 = fmaf(-2.f, (b0 + b1) + (b2 + b3), cn);
      if (d0 < best0) { best0 = d0; bk0 = kbase + kk; }  // strict < tie-break
      if (d1 < best1) { best1 = d1; bk1 = kbase + kk; }
    }
  }

  sd[kg][pair * 2] = best0; sk[kg][pair * 2] = bk0;
  sd[kg][pair * 2 + 1] = best1; sk[kg][pair * 2 + 1] = bk1;
  __syncthreads();

  float lsum = 0.f;
  if (kg == 0) {
    // Merge the 4 K-quarters in ascending-k order (strict < keeps lowest k).
#pragma unroll
    for (int g = 1; g < 4; ++g) {
      float d = sd[g][pair * 2]; int k = sk[g][pair * 2];
      if (d < best0) { best0 = d; bk0 = k; }
      d = sd[g][pair * 2 + 1]; k = sk[g][pair * 2 + 1];
      if (d < best1) { best1 = d; bk1 = k; }
    }
    idx[n0] = bk0; idx[n0 + 1] = bk1;
    atomicAdd(&hist[bk0], 1);
    atomicAdd(&hist[bk1], 1);

    // quantized = codebook[bestk]; straight-through out = x + (q - x)
    const float4* q0 = (const float4*)(cb + (size_t)bk0 * 64);
    const float4* q1 = (const float4*)(cb + (size_t)bk1 * 64);
    float* outq = out + Q_OFF + ((size_t)b << 18) + hw;
#pragma unroll
    for (int c4 = 0; c4 < 16; ++c4) {
      float4 qa = q0[c4];
      float4 qb = q1[c4];
      float qav[4] = {qa.x, qa.y, qa.z, qa.w};
      float qbv[4] = {qb.x, qb.y, qb.z, qb.w};
#pragma unroll
      for (int j = 0; j < 4; ++j) {
        int c = c4 * 4 + j;
        float f0 = qav[j] - x0[c];
        float f1 = qbv[j] - x1[c];
        lsum += f0 * f0 + f1 * f1;
        *(float2*)(outq + ((size_t)c << 12)) = make_float2(x0[c] + f0, x1[c] + f1);
      }
    }
  }

  // Deterministic block tree-reduction of loss partials (kg==0 wave only).
  __syncthreads();
  float* red = &sd[0][0];
  if (kg == 0) red[pair] = lsum;
  __syncthreads();
#pragma unroll
  for (int s = 32; s > 0; s >>= 1) {
    if (tid < s) red[tid] += red[tid + s];
    __syncthreads();
  }
  if (tid == 0) partial[blockIdx.x] = red[0];
}

__global__ __launch_bounds__(1024) void k2_finalize(const int* __restrict__ hist,
                                                    const float* __restrict__ partial,
                                                    float* __restrict__ out) {
  __shared__ float red[1024];
  int tid = threadIdx.x;

  // loss = 0.25 * mean((q-x)^2)
  red[tid] = partial[tid];
  __syncthreads();
  for (int s = 512; s > 0; s >>= 1) {
    if (tid < s) red[tid] += red[tid + s];
    __syncthreads();
  }
  if (tid == 0) out[0] = 0.25f * (red[0] / LOSS_N);
  __syncthreads();

  // perplexity = exp(-sum p*log(p+1e-10)), p = count / N
  float p = (float)hist[tid] * (1.0f / 131072.0f);  // 2^-17: exact
  red[tid] = p * logf(p + 1e-10f);
  __syncthreads();
  for (int s = 512; s > 0; s >>= 1) {
    if (tid < s) red[tid] += red[tid + s];
    __syncthreads();
  }
  if (tid == 0) out[PERP_OFF] = expf(-red[0]);
}

__global__ __launch_bounds__(256) void k3_scatter(const int* __restrict__ idx,
                                                  float* __restrict__ out) {
  int n = blockIdx.x * 256 + threadIdx.x;
  int k = idx[n];
  int b = n >> 12;
  int pos = n & 4095;
  out[OH_OFF + ((((size_t)b << 10) + k) << 12) + pos] = 1.0f;
}

extern "C" void kernel_launch(void* const* d_in, const int* in_sizes, int n_in,
                              void* d_out, int out_size, void* d_ws, size_t ws_size,
                              hipStream_t stream) {
  const float* in = (const float*)d_in[0];
  const float* cb = (const float*)d_in[1];
  float* out = (float*)d_out;

  float* cnorm   = (float*)d_ws;
  int*   hist    = (int*)d_ws + 1024;
  float* partial = (float*)d_ws + 2048;
  int*   idx     = (int*)d_ws + 3072;

  k0_prep<<<4, 256, 0, stream>>>(cb, cnorm, hist);
  k1_main<<<NBLK, TB, 0, stream>>>(in, cb, cnorm, hist, partial, idx, out);
  k2_finalize<<<1, 1024, 0, stream>>>(hist, partial, out);
  k3_scatter<<<512, 256, 0, stream>>>(idx, out);
}

// Round 4
// 268.583 us; speedup vs baseline: 2.3231x; 1.3029x over previous
//
#include <hip/hip_runtime.h>
#include <math.h>

// Problem: inputs (32,64,64,64) BCHW fp32, codebook (1024,64) fp32
// out: [loss][q_st 8388608][perp][one-hot 134217728] fp32
typedef _Float16 half8 __attribute__((ext_vector_type(8)));
typedef float f32x4 __attribute__((ext_vector_type(4)));

#define NBLK     1024
#define Q_OFF    1
#define PERP_OFF 8388609
#define OH_OFF   8388610
#define LOSS_N   8388608.0f

// ws byte layout:
// [0,4096)        cnorm (1024 f32)
// [4096,8192)     hist  (1024 int)
// [8192,12288)    partial (1024 f32)
// [16384,278528)  cb2: 8 chunks x {hi[128 codes][128B], lo[128][128B]} fp16,
//                 16B-block XOR-swizzled within each 128B row
#define CB2_OFF_B 16384

__global__ __launch_bounds__(256) void k0_prep(const float* __restrict__ cb,
                                               float* __restrict__ cnorm,
                                               int* __restrict__ hist,
                                               char* __restrict__ cb2) {
  int k = blockIdx.x * 256 + threadIdx.x;   // grid=4 -> k in [0,1024)
  hist[k] = 0;
  const float* row = cb + (size_t)k * 64;
  const float4* r4 = (const float4*)row;
  float s = 0.f;
#pragma unroll
  for (int i = 0; i < 16; ++i) {
    float4 v = r4[i];
    s += v.x * v.x + v.y * v.y + v.z * v.z + v.w * v.w;
  }
  cnorm[k] = s;

  // fp16 hi/lo split into swizzled chunk layout (chunk = 128 codes).
  int chunk = k >> 7, c = k & 127;
  int xv = (c & 7) << 4;
  char* base = cb2 + chunk * 32768 + c * 128;
#pragma unroll
  for (int d16 = 0; d16 < 8; ++d16) {
    half8 hh, ll;
#pragma unroll
    for (int i = 0; i < 8; ++i) {
      float v = row[d16 * 8 + i];
      _Float16 h = (_Float16)v;
      hh[i] = h;
      ll[i] = (_Float16)(v - (float)h);
    }
    int off = (d16 * 16) ^ xv;
    *(half8*)(base + off) = hh;          // hi term
    *(half8*)(base + 16384 + off) = ll;  // lo term
  }
}

// Block = 256 thr (4 waves) = 128 points (b fixed, hw window of 128).
// Wave w owns points w*32..+32 as 2 MFMA A-tiles (fp16 hi/lo in VGPRs) and
// scans all 1024 codes in 8 LDS-staged chunks. dist = ||c||^2 - 2*x.c via
// 3-term fp16-split MFMA (~fp32 accuracy). One-hot zero-fill of this block's
// own slab is interleaved with the MFMA tiles; ones written in the epilogue.
__global__ __launch_bounds__(256, 4) void k1_main(
    const float* __restrict__ in, const float* __restrict__ cb,
    const uint4* __restrict__ cb2, const float* __restrict__ cnorm,
    int* __restrict__ hist, float* __restrict__ partial,
    float* __restrict__ out) {
  __shared__ uint4 lds_cb[2048];   // 32 KiB codebook chunk (hi 16K | lo 16K)
  __shared__ int bestk_s[128];
  __shared__ float red[256];

  const int tid = threadIdx.x;
  const int bid = blockIdx.x;
  const int w = tid >> 6, l = tid & 63, q = l & 15, g = l >> 4;
  const int b = bid >> 5;
  const int hw0 = (bid & 31) << 7;

  // ---- A fragments: 2 point-tiles x 2 ksteps, fp16 hi/lo ----
  // layout: lane holds A[row=q][k = g*8+i (+32 for ks=1)]
  half8 ah[2][2], al[2][2];
  {
    const float* xb = in + ((size_t)b << 18);
#pragma unroll
    for (int a = 0; a < 2; ++a) {
      const int hw = hw0 + w * 32 + a * 16 + q;
#pragma unroll
      for (int ks = 0; ks < 2; ++ks) {
#pragma unroll
        for (int i = 0; i < 8; ++i) {
          float v = xb[((size_t)(ks * 32 + g * 8 + i) << 12) + hw];
          _Float16 h = (_Float16)v;
          ah[a][ks][i] = h;
          al[a][ks][i] = (_Float16)(v - (float)h);
        }
      }
    }
  }

  float bd0[4], bd1[4];
  int bk0[4], bk1[4];
#pragma unroll
  for (int j = 0; j < 4; ++j) { bd0[j] = bd1[j] = 3.4e38f; bk0[j] = bk1[j] = 0; }

  const int xorv = (q & 7) << 4;
  const int offh0 = q * 128 + ((g * 16) ^ xorv);        // ks=0 (dims 0..31)
  const int offh1 = q * 128 + ((64 + g * 16) ^ xorv);   // ks=1 (dims 32..63)
  float* ohrow0 = out + OH_OFF + ((size_t)b << 22) + hw0;
  const float2 z2 = make_float2(0.f, 0.f);

  for (int ch = 0; ch < 8; ++ch) {
    __syncthreads();
    const uint4* src = cb2 + (size_t)ch * 2048;   // linear copy (pre-swizzled)
#pragma unroll
    for (int i = 0; i < 8; ++i) lds_cb[i * 256 + tid] = src[i * 256 + tid];
    __syncthreads();

    const char* base = (const char*)lds_cb;
    const int cbase = ch << 7;
#pragma unroll
    for (int tb = 0; tb < 8; ++tb) {
      // interleave 4 one-hot zero rows (this block's own slab)
      {
        const int row = cbase + w * 32 + tb * 4;
#pragma unroll
        for (int r = 0; r < 4; ++r)
          ((float2*)(ohrow0 + (size_t)(row + r) * 4096))[l] = z2;
      }
      const char* tbase = base + tb * 2048;
      half8 bh0 = *(const half8*)(tbase + offh0);
      half8 bh1 = *(const half8*)(tbase + offh1);
      half8 bl0 = *(const half8*)(tbase + 16384 + offh0);
      half8 bl1 = *(const half8*)(tbase + 16384 + offh1);
      const int code = cbase + tb * 16 + q;
      const float cn = cnorm[code];
      const f32x4 z = {0.f, 0.f, 0.f, 0.f};
      // a = 0: dot = xh.ch + xl.ch + xh.cl  (two 3-chains for ILP)
      f32x4 s = __builtin_amdgcn_mfma_f32_16x16x32_f16(ah[0][0], bh0, z, 0, 0, 0);
      s = __builtin_amdgcn_mfma_f32_16x16x32_f16(al[0][0], bh0, s, 0, 0, 0);
      s = __builtin_amdgcn_mfma_f32_16x16x32_f16(ah[0][0], bl0, s, 0, 0, 0);
      f32x4 t = __builtin_amdgcn_mfma_f32_16x16x32_f16(ah[0][1], bh1, z, 0, 0, 0);
      t = __builtin_amdgcn_mfma_f32_16x16x32_f16(al[0][1], bh1, t, 0, 0, 0);
      t = __builtin_amdgcn_mfma_f32_16x16x32_f16(ah[0][1], bl1, t, 0, 0, 0);
      s = s + t;
#pragma unroll
      for (int j = 0; j < 4; ++j) {
        float d = fmaf(-2.f, s[j], cn);
        if (d < bd0[j]) { bd0[j] = d; bk0[j] = code; }
      }
      // a = 1
      f32x4 u = __builtin_amdgcn_mfma_f32_16x16x32_f16(ah[1][0], bh0, z, 0, 0, 0);
      u = __builtin_amdgcn_mfma_f32_16x16x32_f16(al[1][0], bh0, u, 0, 0, 0);
      u = __builtin_amdgcn_mfma_f32_16x16x32_f16(ah[1][0], bl0, u, 0, 0, 0);
      f32x4 v = __builtin_amdgcn_mfma_f32_16x16x32_f16(ah[1][1], bh1, z, 0, 0, 0);
      v = __builtin_amdgcn_mfma_f32_16x16x32_f16(al[1][1], bh1, v, 0, 0, 0);
      v = __builtin_amdgcn_mfma_f32_16x16x32_f16(ah[1][1], bl1, v, 0, 0, 0);
      u = u + v;
#pragma unroll
      for (int j = 0; j < 4; ++j) {
        float d = fmaf(-2.f, u[j], cn);
        if (d < bd1[j]) { bd1[j] = d; bk1[j] = code; }
      }
    }
  }

  // Butterfly argmin over the 16 column-residues (lanes sharing g).
  // Equal distances -> lower code index (reference: first-index argmax).
#pragma unroll
  for (int m = 1; m < 16; m <<= 1) {
#pragma unroll
    for (int j = 0; j < 4; ++j) {
      float od = __shfl_xor(bd0[j], m, 64);
      int ok = __shfl_xor(bk0[j], m, 64);
      if (od < bd0[j] || (od == bd0[j] && ok < bk0[j])) { bd0[j] = od; bk0[j] = ok; }
      od = __shfl_xor(bd1[j], m, 64);
      ok = __shfl_xor(bk1[j], m, 64);
      if (od < bd1[j] || (od == bd1[j] && ok < bk1[j])) { bd1[j] = od; bk1[j] = ok; }
    }
  }
  if (q == 0) {
#pragma unroll
    for (int j = 0; j < 4; ++j) {
      bestk_s[w * 32 + g * 4 + j] = bk0[j];
      bestk_s[w * 32 + 16 + g * 4 + j] = bk1[j];
    }
  }
  __syncthreads();   // also drains this block's zero-fill stores (vmcnt)

  // ---- Epilogue: ones, hist, q_st, loss ----
  const int p = tid & 127, hf = tid >> 7;
  const int kq = bestk_s[p];
  if (hf == 0) {
    out[OH_OFF + ((size_t)b << 22) + ((size_t)kq << 12) + hw0 + p] = 1.0f;
    atomicAdd(&hist[kq], 1);   // integer: deterministic
  }
  float lsum = 0.f;
  {
    const float* xb = in + ((size_t)b << 18) + hw0 + p;
    float* yb = out + Q_OFF + ((size_t)b << 18) + hw0 + p;
    const float* qrow = cb + (size_t)kq * 64;
#pragma unroll
    for (int c = 0; c < 32; ++c) {
      const int cc = hf * 32 + c;
      float x = xb[(size_t)cc << 12];
      float f = qrow[cc] - x;
      lsum += f * f;
      yb[(size_t)cc << 12] = x + f;   // fl(x + fl(q-x)) as reference
    }
  }
  red[tid] = lsum;
  __syncthreads();
#pragma unroll
  for (int sft = 128; sft > 0; sft >>= 1) {
    if (tid < sft) red[tid] += red[tid + sft];
    __syncthreads();
  }
  if (tid == 0) partial[bid] = red[0];
}

__global__ __launch_bounds__(1024) void k2_finalize(const int* __restrict__ hist,
                                                    const float* __restrict__ partial,
                                                    float* __restrict__ out) {
  __shared__ float red[1024];
  int tid = threadIdx.x;

  // loss = 0.25 * mean((q-x)^2)
  red[tid] = partial[tid];
  __syncthreads();
  for (int s = 512; s > 0; s >>= 1) {
    if (tid < s) red[tid] += red[tid + s];
    __syncthreads();
  }
  if (tid == 0) out[0] = 0.25f * (red[0] / LOSS_N);
  __syncthreads();

  // perplexity = exp(-sum p*log(p+1e-10)), p = count / 2^17 (exact)
  float pr = (float)hist[tid] * (1.0f / 131072.0f);
  red[tid] = pr * logf(pr + 1e-10f);
  __syncthreads();
  for (int s = 512; s > 0; s >>= 1) {
    if (tid < s) red[tid] += red[tid + s];
    __syncthreads();
  }
  if (tid == 0) out[PERP_OFF] = expf(-red[0]);
}

extern "C" void kernel_launch(void* const* d_in, const int* in_sizes, int n_in,
                              void* d_out, int out_size, void* d_ws, size_t ws_size,
                              hipStream_t stream) {
  const float* in = (const float*)d_in[0];
  const float* cb = (const float*)d_in[1];
  float* out = (float*)d_out;

  float* cnorm   = (float*)d_ws;
  int*   hist    = (int*)d_ws + 1024;
  float* partial = (float*)d_ws + 2048;
  char*  cb2b    = (char*)d_ws + CB2_OFF_B;

  k0_prep<<<4, 256, 0, stream>>>(cb, cnorm, hist, cb2b);
  k1_main<<<NBLK, 256, 0, stream>>>(in, cb, (const uint4*)cb2b, cnorm, hist,
                                    partial, out);
  k2_finalize<<<1, 1024, 0, stream>>>(hist, partial, out);
}

// Round 5
// 224.945 us; speedup vs baseline: 2.7738x; 1.1940x over previous
//
#include <hip/hip_runtime.h>
#include <math.h>

// Problem: inputs (32,64,64,64) BCHW fp32, codebook (1024,64) fp32
// out: [loss][q_st 8388608][perp][one-hot 134217728] fp32
typedef _Float16 half8 __attribute__((ext_vector_type(8)));
typedef float f32x4 __attribute__((ext_vector_type(4)));
typedef float f32x2 __attribute__((ext_vector_type(2)));

#define NBLK     1024
#define Q_OFF    1
#define PERP_OFF 8388609
#define OH_OFF   8388610
#define LOSS_N   8388608.0f

// ws byte layout:
// [0,4096)         cnorm (1024 f32)
// [4096,8192)      hist  (1024 int)
// [8192,12288)     partial (1024 f32)
// [16384,278528)   cb2: 64 tiles x 4KB; tile = 16 codes:
//                  [hi ks0 1KB | hi ks1 1KB | lo ks0 1KB | lo ks1 1KB],
//                  within each 1KB: code c (0..15) x 64B (dims g*8+i, g=0..3)
// [278528,802816)  idx (131072 int)
#define CB2_OFF_B 16384
#define IDX_OFF_W 69632   // 278528/4

__global__ __launch_bounds__(256) void k0_prep(const float* __restrict__ cb,
                                               float* __restrict__ cnorm,
                                               int* __restrict__ hist,
                                               char* __restrict__ cb2) {
  int k = blockIdx.x * 256 + threadIdx.x;   // grid=4 -> k in [0,1024)
  hist[k] = 0;
  const float* row = cb + (size_t)k * 64;
  const float4* r4 = (const float4*)row;
  float s = 0.f;
#pragma unroll
  for (int i = 0; i < 16; ++i) {
    float4 v = r4[i];
    s += v.x * v.x + v.y * v.y + v.z * v.z + v.w * v.w;
  }
  cnorm[k] = s;

  // fp16 hi/lo split, tile-contiguous layout for dense per-wave loads.
  int tile = k >> 4, c = k & 15;
  char* base = cb2 + tile * 4096;
#pragma unroll
  for (int d16 = 0; d16 < 8; ++d16) {
    half8 hh, ll;
#pragma unroll
    for (int i = 0; i < 8; ++i) {
      float v = row[d16 * 8 + i];
      _Float16 h = (_Float16)v;
      hh[i] = h;
      ll[i] = (_Float16)(v - (float)h);
    }
    int off = (d16 >> 2) * 1024 + c * 64 + (d16 & 3) * 16;  // ks | code | g
    *(half8*)(base + off) = hh;          // hi
    *(half8*)(base + 2048 + off) = ll;   // lo
  }
}

// Block = 256 thr (4 waves) = 128 points (b fixed, 128-wide hw window).
// Wave w owns 32 points as 2 MFMA A-tiles (fp16 hi/lo in VGPRs) and scans all
// 1024 codes in 64 tiles, B-fragments loaded straight from L2 (codebook is
// 256KB, L2-resident -> no LDS, NO barriers in the main loop). dist =
// ||c||^2 - 2*x.c via 3-term fp16-split MFMA (~fp32 accuracy). The block's
// contiguous 512KB slab of the one-hot zero-fill is interleaved via
// nontemporal float2 stores; the 1.0s are scattered by k3 afterwards.
__global__ __launch_bounds__(256, 4) void k1_main(
    const float* __restrict__ in, const float* __restrict__ cb,
    const char* __restrict__ cb2, const float* __restrict__ cnorm,
    int* __restrict__ hist, float* __restrict__ partial,
    int* __restrict__ idx, float* __restrict__ out) {
  __shared__ int bestk_s[128];
  __shared__ float red[256];

  const int tid = threadIdx.x;
  const int bid = blockIdx.x;
  const int w = tid >> 6, l = tid & 63, q = l & 15, g = l >> 4;
  const int b = bid >> 5;
  const int hw0 = (bid & 31) << 7;

  // ---- A fragments: 2 point-tiles x 2 ksteps, fp16 hi/lo ----
  // lane holds A[row=q][k = g*8+i (+32 for ks=1)]
  half8 ah[2][2], al[2][2];
  {
    const float* xb = in + ((size_t)b << 18);
#pragma unroll
    for (int a = 0; a < 2; ++a) {
      const int hw = hw0 + w * 32 + a * 16 + q;
#pragma unroll
      for (int ks = 0; ks < 2; ++ks) {
#pragma unroll
        for (int i = 0; i < 8; ++i) {
          float v = xb[((size_t)(ks * 32 + g * 8 + i) << 12) + hw];
          _Float16 h = (_Float16)v;
          ah[a][ks][i] = h;
          al[a][ks][i] = (_Float16)(v - (float)h);
        }
      }
    }
  }

  float bd0[4], bd1[4];
  int bk0[4], bk1[4];
#pragma unroll
  for (int j = 0; j < 4; ++j) { bd0[j] = bd1[j] = 3.4e38f; bk0[j] = bk1[j] = 0; }

  const int boff = q * 64 + g * 16;            // dense 1KB per wave-load
  f32x2* ohz = (f32x2*)(out + OH_OFF);
  const f32x2 z2 = {0.f, 0.f};
  const size_t slab = (size_t)bid * 65536 + tid;   // float2 units

  for (int tb = 0; tb < 64; ++tb) {
    const char* tbase = cb2 + tb * 4096 + boff;
    half8 bh0 = *(const half8*)(tbase);
    half8 bh1 = *(const half8*)(tbase + 1024);
    half8 bl0 = *(const half8*)(tbase + 2048);
    half8 bl1 = *(const half8*)(tbase + 3072);
    const int code = tb * 16 + q;
    const float cn = cnorm[code];
    const f32x4 z = {0.f, 0.f, 0.f, 0.f};
    // a = 0: dot = xh.ch + xl.ch + xh.cl  (two 3-chains for ILP)
    f32x4 s = __builtin_amdgcn_mfma_f32_16x16x32_f16(ah[0][0], bh0, z, 0, 0, 0);
    s = __builtin_amdgcn_mfma_f32_16x16x32_f16(al[0][0], bh0, s, 0, 0, 0);
    s = __builtin_amdgcn_mfma_f32_16x16x32_f16(ah[0][0], bl0, s, 0, 0, 0);
    f32x4 t = __builtin_amdgcn_mfma_f32_16x16x32_f16(ah[0][1], bh1, z, 0, 0, 0);
    t = __builtin_amdgcn_mfma_f32_16x16x32_f16(al[0][1], bh1, t, 0, 0, 0);
    t = __builtin_amdgcn_mfma_f32_16x16x32_f16(ah[0][1], bl1, t, 0, 0, 0);
    s = s + t;
#pragma unroll
    for (int j = 0; j < 4; ++j) {
      float d = fmaf(-2.f, s[j], cn);
      if (d < bd0[j]) { bd0[j] = d; bk0[j] = code; }
    }
    // a = 1
    f32x4 u = __builtin_amdgcn_mfma_f32_16x16x32_f16(ah[1][0], bh0, z, 0, 0, 0);
    u = __builtin_amdgcn_mfma_f32_16x16x32_f16(al[1][0], bh0, u, 0, 0, 0);
    u = __builtin_amdgcn_mfma_f32_16x16x32_f16(ah[1][0], bl0, u, 0, 0, 0);
    f32x4 v = __builtin_amdgcn_mfma_f32_16x16x32_f16(ah[1][1], bh1, z, 0, 0, 0);
    v = __builtin_amdgcn_mfma_f32_16x16x32_f16(al[1][1], bh1, v, 0, 0, 0);
    v = __builtin_amdgcn_mfma_f32_16x16x32_f16(ah[1][1], bl1, v, 0, 0, 0);
    u = u + v;
#pragma unroll
    for (int j = 0; j < 4; ++j) {
      float d = fmaf(-2.f, u[j], cn);
      if (d < bd1[j]) { bd1[j] = d; bk1[j] = code; }
    }
    // Linear nontemporal zero-fill: 4 x float2 per thread per tile
    // (fire-and-forget; no barrier in this loop -> no vmcnt(0) drain).
    {
      size_t zb = slab + (size_t)tb * 1024;
#pragma unroll
      for (int r = 0; r < 4; ++r)
        __builtin_nontemporal_store(z2, &ohz[zb + r * 256]);
    }
  }

  // Butterfly argmin across the 16 code-residues (q = lane&15).
  // Equal distances -> lower code index (reference: first-index argmax).
#pragma unroll
  for (int m = 1; m < 16; m <<= 1) {
#pragma unroll
    for (int j = 0; j < 4; ++j) {
      float od = __shfl_xor(bd0[j], m, 64);
      int ok = __shfl_xor(bk0[j], m, 64);
      if (od < bd0[j] || (od == bd0[j] && ok < bk0[j])) { bd0[j] = od; bk0[j] = ok; }
      od = __shfl_xor(bd1[j], m, 64);
      ok = __shfl_xor(bk1[j], m, 64);
      if (od < bd1[j] || (od == bd1[j] && ok < bk1[j])) { bd1[j] = od; bk1[j] = ok; }
    }
  }
  if (q == 0) {
#pragma unroll
    for (int j = 0; j < 4; ++j) {
      bestk_s[w * 32 + g * 4 + j] = bk0[j];          // a=0 tile
      bestk_s[w * 32 + 16 + g * 4 + j] = bk1[j];     // a=1 tile
    }
  }
  __syncthreads();

  // ---- Epilogue: idx, hist, q_st, loss ----
  const int p = tid & 127, hf = tid >> 7;
  const int kq = bestk_s[p];
  if (hf == 0) {
    idx[bid * 128 + p] = kq;
    atomicAdd(&hist[kq], 1);   // integer: deterministic
  }
  float lsum = 0.f;
  {
    const float* xb = in + ((size_t)b << 18) + hw0 + p;
    float* yb = out + Q_OFF + ((size_t)b << 18) + hw0 + p;
    const float* qrow = cb + (size_t)kq * 64;
#pragma unroll
    for (int c = 0; c < 32; ++c) {
      const int cc = hf * 32 + c;
      float x = xb[(size_t)cc << 12];
      float f = qrow[cc] - x;
      lsum += f * f;
      yb[(size_t)cc << 12] = x + f;   // fl(x + fl(q-x)) as reference
    }
  }
  red[tid] = lsum;
  __syncthreads();
#pragma unroll
  for (int sft = 128; sft > 0; sft >>= 1) {
    if (tid < sft) red[tid] += red[tid + sft];
    __syncthreads();
  }
  if (tid == 0) partial[bid] = red[0];
}

__global__ __launch_bounds__(1024) void k2_finalize(const int* __restrict__ hist,
                                                    const float* __restrict__ partial,
                                                    float* __restrict__ out) {
  __shared__ float red[1024];
  int tid = threadIdx.x;

  // loss = 0.25 * mean((q-x)^2)
  red[tid] = partial[tid];
  __syncthreads();
  for (int s = 512; s > 0; s >>= 1) {
    if (tid < s) red[tid] += red[tid + s];
    __syncthreads();
  }
  if (tid == 0) out[0] = 0.25f * (red[0] / LOSS_N);
  __syncthreads();

  // perplexity = exp(-sum p*log(p+1e-10)), p = count / 2^17 (exact)
  float pr = (float)hist[tid] * (1.0f / 131072.0f);
  red[tid] = pr * logf(pr + 1e-10f);
  __syncthreads();
  for (int s = 512; s > 0; s >>= 1) {
    if (tid < s) red[tid] += red[tid + s];
    __syncthreads();
  }
  if (tid == 0) out[PERP_OFF] = expf(-red[0]);
}

__global__ __launch_bounds__(256) void k3_scatter(const int* __restrict__ idx,
                                                  float* __restrict__ out) {
  int n = blockIdx.x * 256 + threadIdx.x;
  int k = idx[n];
  int b = n >> 12;
  int pos = n & 4095;
  out[OH_OFF + ((((size_t)b << 10) + (size_t)k) << 12) + pos] = 1.0f;
}

extern "C" void kernel_launch(void* const* d_in, const int* in_sizes, int n_in,
                              void* d_out, int out_size, void* d_ws, size_t ws_size,
                              hipStream_t stream) {
  const float* in = (const float*)d_in[0];
  const float* cb = (const float*)d_in[1];
  float* out = (float*)d_out;

  float* cnorm   = (float*)d_ws;
  int*   hist    = (int*)d_ws + 1024;
  float* partial = (float*)d_ws + 2048;
  char*  cb2b    = (char*)d_ws + CB2_OFF_B;
  int*   idx     = (int*)d_ws + IDX_OFF_W;

  k0_prep<<<4, 256, 0, stream>>>(cb, cnorm, hist, cb2b);
  k1_main<<<NBLK, 256, 0, stream>>>(in, cb, cb2b, cnorm, hist, partial, idx, out);
  k2_finalize<<<1, 1024, 0, stream>>>(hist, partial, out);
  k3_scatter<<<512, 256, 0, stream>>>(idx, out);
}